// Round 1
// baseline (351.020 us; speedup 1.0000x reference)
//
#include <hip/hip_runtime.h>
#include <hip/hip_bf16.h>

typedef __attribute__((ext_vector_type(8))) short short8;
typedef __attribute__((ext_vector_type(4))) float f32x4;

#define DEV static __device__ __forceinline__

constexpr int S_LEN   = 2048;
constexpr int DMODEL  = 1024;
constexpr int NHEAD   = 16;
constexpr int DHEAD   = 64;
constexpr int NBATCH  = 2;
constexpr int BHN     = NBATCH * NHEAD;   // 32
constexpr int MROWS   = NBATCH * S_LEN;   // 4096
constexpr int KDIM    = DMODEL;
constexpr int NDIM    = DMODEL;
constexpr int BM = 128, BN = 128, BK = 32;

DEV unsigned short f2b(float f) {
  __hip_bfloat16 h = __float2bfloat16(f);
  return __builtin_bit_cast(unsigned short, h);
}
DEV unsigned pk2(float a, float b) {
  return (unsigned)f2b(a) | ((unsigned)f2b(b) << 16);
}
DEV short8 ld8(const unsigned short* p) {
  return *reinterpret_cast<const short8*>(p);
}

struct GArgs {
  const float* A[3];
  const float* W[3];
  const float* bia[3];
  void* out[3];
  int epi[3];   // 0=Q(scaled) 1=K 2=V(transposed) 3=final(fp32)
};

// C[row,col] = sum_k A[row,k] * W[col,k] + bia[col]  (NT GEMM, fp32 in, bf16 MFMA)
__global__ __launch_bounds__(256, 2) void gemm_bt(GArgs g) {
  const int z = blockIdx.z;
  const float* __restrict__ A   = g.A[z];
  const float* __restrict__ W   = g.W[z];
  const float* __restrict__ bia = g.bia[z];
  const int epi = g.epi[z];
  const int bm = blockIdx.y, bn = blockIdx.x;
  const int tid = threadIdx.x, lane = tid & 63, wid = tid >> 6;
  const int wr = wid >> 1, wc = wid & 1;          // 2x2 waves, 64x64 each
  const int fr = lane & 15, gq = lane >> 4;

  __shared__ unsigned short As[BM][BK];   // 8 KB
  __shared__ unsigned short Bs[BN][BK];   // 8 KB

  f32x4 acc[4][4] = {};
  f32x4 ra[4], rb[4];

  const int r0 = tid >> 3;   // rows r0 + 32*i
  const int cg = tid & 7;    // 4-float column group

  auto loadAB = [&](int kt) {
    #pragma unroll
    for (int i = 0; i < 4; ++i) {
      const int row = r0 + 32 * i;
      ra[i] = *reinterpret_cast<const f32x4*>(A + (size_t)(bm*BM + row)*KDIM + kt*BK + cg*4);
      rb[i] = *reinterpret_cast<const f32x4*>(W + (size_t)(bn*BN + row)*KDIM + kt*BK + cg*4);
    }
  };
  auto storeAB = [&]() {
    #pragma unroll
    for (int i = 0; i < 4; ++i) {
      const int row = r0 + 32 * i;
      unsigned* pa = reinterpret_cast<unsigned*>(&As[row][cg*4]);
      pa[0] = pk2(ra[i][0], ra[i][1]);
      pa[1] = pk2(ra[i][2], ra[i][3]);
      unsigned* pb = reinterpret_cast<unsigned*>(&Bs[row][cg*4]);
      pb[0] = pk2(rb[i][0], rb[i][1]);
      pb[1] = pk2(rb[i][2], rb[i][3]);
    }
  };

  loadAB(0);
  for (int kt = 0; kt < KDIM / BK; ++kt) {
    __syncthreads();
    storeAB();
    __syncthreads();
    if (kt + 1 < KDIM / BK) loadAB(kt + 1);
    short8 af[4], bf[4];
    #pragma unroll
    for (int i = 0; i < 4; ++i) af[i] = ld8(&As[wr*64 + i*16 + fr][gq*8]);
    #pragma unroll
    for (int j = 0; j < 4; ++j) bf[j] = ld8(&Bs[wc*64 + j*16 + fr][gq*8]);
    #pragma unroll
    for (int i = 0; i < 4; ++i)
      #pragma unroll
      for (int j = 0; j < 4; ++j)
        acc[i][j] = __builtin_amdgcn_mfma_f32_16x16x32_bf16(af[i], bf[j], acc[i][j], 0, 0, 0);
  }

  // epilogue: C row = gq*4+r, col = fr (within each 16x16 fragment)
  #pragma unroll
  for (int i = 0; i < 4; ++i) {
    #pragma unroll
    for (int j = 0; j < 4; ++j) {
      #pragma unroll
      for (int r = 0; r < 4; ++r) {
        const int row = bm*BM + wr*64 + i*16 + gq*4 + r;
        const int col = bn*BN + wc*64 + j*16 + fr;
        float v = acc[i][j][r] + bia[col];
        if (epi == 3) {
          ((float*)g.out[z])[(size_t)row * NDIM + col] = v;
        } else {
          const int b = row >> 11, s = row & (S_LEN - 1);
          const int h = col >> 6,  dh = col & (DHEAD - 1);
          unsigned short* O = (unsigned short*)g.out[z];
          if (epi == 0)      O[((size_t)(b*NHEAD + h)*S_LEN + s)*DHEAD + dh] = f2b(v * 0.125f);
          else if (epi == 1) O[((size_t)(b*NHEAD + h)*S_LEN + s)*DHEAD + dh] = f2b(v);
          else               O[((size_t)(b*NHEAD + h)*DHEAD + dh)*S_LEN + s] = f2b(v);
        }
      }
    }
  }
}

// Flash attention: Qp,Kp [bh][s][64] bf16 (Q pre-scaled by 1/8), Vt [bh][64][s] bf16.
// Block: 4 waves x 16 q-rows; per iter 32 keys. Swapped QK^T: mfma(K, Q).
__global__ __launch_bounds__(256, 2) void attn_fwd(const unsigned short* __restrict__ Qp,
                                                   const unsigned short* __restrict__ Kp,
                                                   const unsigned short* __restrict__ Vt,
                                                   float* __restrict__ AO) {
  const int bh = blockIdx.y, qt = blockIdx.x;
  const int tid = threadIdx.x, lane = tid & 63, wid = tid >> 6;
  const int fr = lane & 15, gq = lane >> 4;
  const unsigned short* Qh = Qp + (size_t)bh * S_LEN * DHEAD;
  const unsigned short* Kh = Kp + (size_t)bh * S_LEN * DHEAD;
  const unsigned short* Vh = Vt + (size_t)bh * DHEAD * S_LEN;
  const int qbase = qt * 64 + wid * 16;

  short8 qf0 = ld8(Qh + (size_t)(qbase + fr) * DHEAD +      gq * 8);
  short8 qf1 = ld8(Qh + (size_t)(qbase + fr) * DHEAD + 32 + gq * 8);

  float m = -1e30f, l = 0.f;
  f32x4 o[4] = {};
  __shared__ unsigned short P[4][16][32];  // per-wave P tile

  for (int kt = 0; kt < S_LEN / 32; ++kt) {
    const unsigned short* Kb = Kh + (size_t)kt * 32 * DHEAD;
    f32x4 s0 = {}, s1 = {};
    {
      short8 k00 = ld8(Kb + (size_t)fr        * DHEAD +      gq * 8);
      short8 k01 = ld8(Kb + (size_t)fr        * DHEAD + 32 + gq * 8);
      short8 k10 = ld8(Kb + (size_t)(16 + fr) * DHEAD +      gq * 8);
      short8 k11 = ld8(Kb + (size_t)(16 + fr) * DHEAD + 32 + gq * 8);
      s0 = __builtin_amdgcn_mfma_f32_16x16x32_bf16(k00, qf0, s0, 0, 0, 0);
      s0 = __builtin_amdgcn_mfma_f32_16x16x32_bf16(k01, qf1, s0, 0, 0, 0);
      s1 = __builtin_amdgcn_mfma_f32_16x16x32_bf16(k10, qf0, s1, 0, 0, 0);
      s1 = __builtin_amdgcn_mfma_f32_16x16x32_bf16(k11, qf1, s1, 0, 0, 0);
    }
    // s layout: col=fr=q-row, row=gq*4+r = key within 16 (s0: keys 0-15, s1: 16-31)
    float pm = fmaxf(fmaxf(fmaxf(s0[0], s0[1]), fmaxf(s0[2], s0[3])),
                     fmaxf(fmaxf(s1[0], s1[1]), fmaxf(s1[2], s1[3])));
    pm = fmaxf(pm, __shfl_xor(pm, 16));
    pm = fmaxf(pm, __shfl_xor(pm, 32));
    const float mnew = fmaxf(m, pm);
    const float alpha = __expf(m - mnew);
    float p0[4], p1[4];
    float tl = 0.f;
    #pragma unroll
    for (int r = 0; r < 4; ++r) {
      p0[r] = __expf(s0[r] - mnew);
      p1[r] = __expf(s1[r] - mnew);
      tl += p0[r] + p1[r];
    }
    tl += __shfl_xor(tl, 16);
    tl += __shfl_xor(tl, 32);
    l = l * alpha + tl;
    m = mnew;
    #pragma unroll
    for (int r = 0; r < 4; ++r) {
      const float ar = __shfl(alpha, gq * 4 + r);   // alpha for q-row gq*4+r lives in lanes 0-15
      o[0][r] *= ar; o[1][r] *= ar; o[2][r] *= ar; o[3][r] *= ar;
    }
    // repack P (bf16) into A-fragment layout via LDS: P[wid][q][key]
    *(unsigned*)&P[wid][fr][gq*4]          = pk2(p0[0], p0[1]);
    *(unsigned*)&P[wid][fr][gq*4 + 2]      = pk2(p0[2], p0[3]);
    *(unsigned*)&P[wid][fr][16 + gq*4]     = pk2(p1[0], p1[1]);
    *(unsigned*)&P[wid][fr][16 + gq*4 + 2] = pk2(p1[2], p1[3]);
    // same-wave LDS ops are in-order; compiler inserts lgkmcnt before use
    short8 pf = ld8(&P[wid][fr][gq * 8]);
    const unsigned short* Vb = Vh + (size_t)kt * 32 + gq * 8;
    #pragma unroll
    for (int j = 0; j < 4; ++j) {
      short8 vf = ld8(Vb + (size_t)(j * 16 + fr) * S_LEN);
      o[j] = __builtin_amdgcn_mfma_f32_16x16x32_bf16(pf, vf, o[j], 0, 0, 0);
    }
  }

  // o layout: col=fr = dh within 16-tile j, row = gq*4+r = q-row within wave tile
  const int b = bh >> 4, h = bh & 15;
  #pragma unroll
  for (int r = 0; r < 4; ++r) {
    const float lr = __shfl(l, gq * 4 + r);
    const float inv = 1.0f / lr;
    const int srow = qbase + gq * 4 + r;
    float* Op = AO + ((size_t)(b * S_LEN + srow)) * DMODEL + h * DHEAD;
    #pragma unroll
    for (int j = 0; j < 4; ++j) Op[j * 16 + fr] = o[j][r] * inv;
  }
}

extern "C" void kernel_launch(void* const* d_in, const int* in_sizes, int n_in,
                              void* d_out, int out_size, void* d_ws, size_t ws_size,
                              hipStream_t stream) {
  const float* query = (const float*)d_in[0];
  const float* key   = (const float*)d_in[1];
  const float* value = (const float*)d_in[2];
  const float* Wq = (const float*)d_in[3];  const float* bq = (const float*)d_in[4];
  const float* Wk = (const float*)d_in[5];  const float* bk = (const float*)d_in[6];
  const float* Wv = (const float*)d_in[7];  const float* bv = (const float*)d_in[8];
  const float* Wo = (const float*)d_in[9];  const float* bo = (const float*)d_in[10];

  const size_t MB = 1024u * 1024u;
  unsigned short* Qp = (unsigned short*)((char*)d_ws + 0 * MB);   // [32][2048][64] bf16, 8MB
  unsigned short* Kp = (unsigned short*)((char*)d_ws + 8 * MB);   // [32][2048][64] bf16, 8MB
  unsigned short* Vt = (unsigned short*)((char*)d_ws + 16 * MB);  // [32][64][2048] bf16, 8MB
  float*          AO = (float*)((char*)d_ws + 24 * MB);           // [4096][1024] fp32, 16MB

  GArgs g1;
  g1.A[0] = query; g1.A[1] = key; g1.A[2] = value;
  g1.W[0] = Wq;    g1.W[1] = Wk;  g1.W[2] = Wv;
  g1.bia[0] = bq;  g1.bia[1] = bk; g1.bia[2] = bv;
  g1.out[0] = Qp;  g1.out[1] = Kp; g1.out[2] = Vt;
  g1.epi[0] = 0;   g1.epi[1] = 1;  g1.epi[2] = 2;
  gemm_bt<<<dim3(NDIM / BN, MROWS / BM, 3), 256, 0, stream>>>(g1);

  attn_fwd<<<dim3(S_LEN / 64, BHN), 256, 0, stream>>>(Qp, Kp, Vt, AO);

  GArgs g2 = {};
  g2.A[0] = AO; g2.W[0] = Wo; g2.bia[0] = bo; g2.out[0] = d_out; g2.epi[0] = 3;
  gemm_bt<<<dim3(NDIM / BN, MROWS / BM, 1), 256, 0, stream>>>(g2);
}

// Round 5
// 190.655 us; speedup vs baseline: 1.8411x; 1.8411x over previous
//
#include <hip/hip_runtime.h>
#include <hip/hip_bf16.h>

typedef __attribute__((ext_vector_type(8))) short short8;
typedef __attribute__((ext_vector_type(4))) float f32x4;
typedef __attribute__((ext_vector_type(16))) float f32x16;
typedef __attribute__((ext_vector_type(4))) int int4v;

#define DEV static __device__ __forceinline__

constexpr int S_LEN   = 2048;
constexpr int DMODEL  = 1024;
constexpr int NHEAD   = 16;
constexpr int DHEAD   = 64;
constexpr int NBATCH  = 2;
constexpr int BHN     = NBATCH * NHEAD;   // 32
constexpr int MROWS   = NBATCH * S_LEN;   // 4096
constexpr int KDIM    = DMODEL;
constexpr int NDIM    = DMODEL;
constexpr int BM = 128, BN = 128, BK = 32;

DEV unsigned short f2b(float f) {
  __hip_bfloat16 h = __float2bfloat16(f);
  return __builtin_bit_cast(unsigned short, h);
}
DEV unsigned pk2(float a, float b) {
  return (unsigned)f2b(a) | ((unsigned)f2b(b) << 16);
}
DEV short8 ld8(const void* p) {
  return *reinterpret_cast<const short8*>(p);
}
DEV f32x16 mfma32(short8 a, short8 b, f32x16 c) {
  return __builtin_amdgcn_mfma_f32_32x32x16_bf16(a, b, c, 0, 0, 0);
}
DEV void gload16(const void* g, void* l) {
  __builtin_amdgcn_global_load_lds(
      (const __attribute__((address_space(1))) unsigned*)g,
      (__attribute__((address_space(3))) unsigned*)l, 16, 0, 0);
}

struct GArgs {
  const float* A[3];
  const float* W[3];
  const float* bia[3];
  void* out[3];
  int epi[3];   // 0=Q(scaled) 1=K 2=V(transposed) 3=final(fp32)
};

// C[row,col] = sum_k A[row,k] * W[col,k] + bia[col]  (NT GEMM, fp32 in, bf16 MFMA)
__global__ __launch_bounds__(256, 2) void gemm_bt(GArgs g) {
  const int z = blockIdx.z;
  const float* __restrict__ A   = g.A[z];
  const float* __restrict__ W   = g.W[z];
  const float* __restrict__ bia = g.bia[z];
  const int epi = g.epi[z];
  const int bm = blockIdx.y, bn = blockIdx.x;
  const int tid = threadIdx.x, lane = tid & 63, wid = tid >> 6;
  const int wr = wid >> 1, wc = wid & 1;          // 2x2 waves, 64x64 each
  const int fr = lane & 15, gq = lane >> 4;

  __shared__ unsigned short As[BM][BK];   // 8 KB
  __shared__ unsigned short Bs[BN][BK];   // 8 KB

  f32x4 acc[4][4] = {};
  f32x4 ra[4], rb[4];

  const int r0 = tid >> 3;   // rows r0 + 32*i
  const int cg = tid & 7;    // 4-float column group

  auto loadAB = [&](int kt) {
    #pragma unroll
    for (int i = 0; i < 4; ++i) {
      const int row = r0 + 32 * i;
      ra[i] = *reinterpret_cast<const f32x4*>(A + (size_t)(bm*BM + row)*KDIM + kt*BK + cg*4);
      rb[i] = *reinterpret_cast<const f32x4*>(W + (size_t)(bn*BN + row)*KDIM + kt*BK + cg*4);
    }
  };
  auto storeAB = [&]() {
    #pragma unroll
    for (int i = 0; i < 4; ++i) {
      const int row = r0 + 32 * i;
      unsigned* pa = reinterpret_cast<unsigned*>(&As[row][cg*4]);
      pa[0] = pk2(ra[i][0], ra[i][1]);
      pa[1] = pk2(ra[i][2], ra[i][3]);
      unsigned* pb = reinterpret_cast<unsigned*>(&Bs[row][cg*4]);
      pb[0] = pk2(rb[i][0], rb[i][1]);
      pb[1] = pk2(rb[i][2], rb[i][3]);
    }
  };

  loadAB(0);
  for (int kt = 0; kt < KDIM / BK; ++kt) {
    __syncthreads();
    storeAB();
    __syncthreads();
    if (kt + 1 < KDIM / BK) loadAB(kt + 1);
    short8 af[4], bf[4];
    #pragma unroll
    for (int i = 0; i < 4; ++i) af[i] = ld8(&As[wr*64 + i*16 + fr][gq*8]);
    #pragma unroll
    for (int j = 0; j < 4; ++j) bf[j] = ld8(&Bs[wc*64 + j*16 + fr][gq*8]);
    #pragma unroll
    for (int i = 0; i < 4; ++i)
      #pragma unroll
      for (int j = 0; j < 4; ++j)
        acc[i][j] = __builtin_amdgcn_mfma_f32_16x16x32_bf16(af[i], bf[j], acc[i][j], 0, 0, 0);
  }

  // epilogue: C row = gq*4+r, col = fr (within each 16x16 fragment)
  #pragma unroll
  for (int i = 0; i < 4; ++i) {
    #pragma unroll
    for (int j = 0; j < 4; ++j) {
      #pragma unroll
      for (int r = 0; r < 4; ++r) {
        const int row = bm*BM + wr*64 + i*16 + gq*4 + r;
        const int col = bn*BN + wc*64 + j*16 + fr;
        float v = acc[i][j][r] + bia[col];
        if (epi == 3) {
          ((float*)g.out[z])[(size_t)row * NDIM + col] = v;
        } else {
          const int b = row >> 11, s = row & (S_LEN - 1);
          const int h = col >> 6,  dh = col & (DHEAD - 1);
          unsigned short* O = (unsigned short*)g.out[z];
          if (epi == 0)      O[((size_t)(b*NHEAD + h)*S_LEN + s)*DHEAD + dh] = f2b(v * 0.125f);
          else if (epi == 1) O[((size_t)(b*NHEAD + h)*S_LEN + s)*DHEAD + dh] = f2b(v);
          else               O[((size_t)(b*NHEAD + h)*DHEAD + dh)*S_LEN + s] = f2b(v);
        }
      }
    }
  }
}

// ---------------------------------------------------------------------------
// Flash attention, 4-wave 32x32 structure (512 blocks -> 2 blocks/CU).
// Qp,Kp [bh][s][64] bf16 (Q pre-scaled by 1/8), Vt [bh][64][s] bf16.
// Block: 4 waves x 32 q-rows = 128 q-rows; KV tile = 64 keys, double-buffered
// LDS, XOR-swizzled via pre-swizzled global source (involution c ^= row&7).
// Swapped QK^T (mfma(K,Q)); exact online softmax; ALL cross-half exchanges
// via __shfl_xor(...,32) (unambiguous semantics) -- no permlane asm.
//
// Fragment ownership (derived): for PV mfma ks, B-word j of lane (ql,hi)
// holds keys 16ks+8hi+2j,+1. Owner half = (j>>1). With w_t = pk2(p[a+2t],
// p[a+2t+1]) and x_t = shfl_xor(w_t,32):
//   hi=0 lane: words [w0, w1, x0, x1]
//   hi=1 lane: words [x2, x3, w2, w3]
// ---------------------------------------------------------------------------
__global__ __launch_bounds__(256, 2) void attn_fwd(
    const unsigned short* __restrict__ Qp,
    const unsigned short* __restrict__ Kp,
    const unsigned short* __restrict__ Vt,
    float* __restrict__ AO) {
  // T1 bijective XCD swizzle: 512 blocks / 8 XCDs -> 4 heads per XCD (2MB L2)
  const int nb = (blockIdx.x & 7) * 64 + (blockIdx.x >> 3);
  const int qt = nb & 15, bh = nb >> 4;
  const int tid = threadIdx.x, lane = tid & 63, wid = tid >> 6;
  const int ql = lane & 31, hi = lane >> 5, l7 = lane & 7, l3 = lane >> 3;

  const unsigned short* Qh = Qp + (size_t)bh * S_LEN * DHEAD;
  const char* Kh = (const char*)(Kp + (size_t)bh * S_LEN * DHEAD);
  const char* Vh = (const char*)(Vt + (size_t)bh * DHEAD * S_LEN);

  __shared__ unsigned short Klds[2][4096];   // [64 keys][64 dh] swizzled, 8KB x2
  __shared__ unsigned short Vlds[2][4096];   // [64 dh][64 keys] swizzled, 8KB x2

  // Q B-fragments (col=q=ql, k-elems = dh d16*16 + hi*8 + 0..7)
  const int q0 = qt * 128 + wid * 32;
  short8 qf[4];
#pragma unroll
  for (int d16 = 0; d16 < 4; ++d16)
    qf[d16] = ld8(Qh + (size_t)(q0 + ql) * DHEAD + d16 * 16 + hi * 8);

  // staging: wave wid stages rows [wid*16, wid*16+16) of each 64-row tile,
  // two gload16 per tile per operand (8 rows each). LDS dest is linear;
  // global source column-chunk pre-swizzled: c_src = l7 ^ (row&7), row&7=l3.
  const int swc = (l7 ^ l3) << 4;
  const char* kS = Kh + (wid * 16 + l3) * 128 + swc;    // K row stride 128B
  const char* vS = Vh + (wid * 16 + l3) * 4096 + swc;   // Vt row stride 4096B
  char* kD0 = (char*)Klds[0] + wid * 2048;
  char* vD0 = (char*)Vlds[0] + wid * 2048;
  char* kD1 = (char*)Klds[1] + wid * 2048;
  char* vD1 = (char*)Vlds[1] + wid * 2048;

  // swizzled read offsets: chunk (j*2+hi) ^ (row&7), row&7 == ql&7 == l7
  int xo[4];
#pragma unroll
  for (int j = 0; j < 4; ++j) xo[j] = ((j * 2 + hi) ^ l7) << 4;

  float m = -1e30f, l = 0.f;
  f32x16 o0 = {}, o1 = {};    // O^T accum: col=q=ql, rows d (+0 / +32)

  gload16(kS, kD0); gload16(kS + 1024, kD0 + 1024);
  gload16(vS, vD0); gload16(vS + 32768, vD0 + 1024);
  __syncthreads();

  for (int kt = 0; kt < S_LEN / 64; ++kt) {
    const int buf = kt & 1;
    if (kt + 1 < S_LEN / 64) {
      const char* kn = kS + (kt + 1) * 8192;
      const char* vn = vS + (kt + 1) * 128;
      char* kD = buf ? kD0 : kD1;
      char* vD = buf ? vD0 : vD1;
      gload16(kn, kD); gload16(kn + 1024, kD + 1024);
      gload16(vn, vD); gload16(vn + 32768, vD + 1024);
    }
    const char* kb = (const char*)Klds[buf] + ql * 128;
    const char* vb = (const char*)Vlds[buf] + ql * 128;

    // QK^T swapped: A=K (row=key), B=Q (col=q) -> S^T[key][q]
    f32x16 st0 = {}, st1 = {};
#pragma unroll
    for (int d16 = 0; d16 < 4; ++d16) {
      short8 k0 = ld8(kb + xo[d16]);
      short8 k1 = ld8(kb + 4096 + xo[d16]);
      st0 = mfma32(k0, qf[d16], st0);
      st1 = mfma32(k1, qf[d16], st1);
    }

    // per-q max over 64 keys: in-lane 32 + cross-half via shfl_xor(32)
    float pm = fmaxf(st0[0], st1[0]);
#pragma unroll
    for (int r = 1; r < 16; ++r) pm = fmaxf(pm, fmaxf(st0[r], st1[r]));
    pm = fmaxf(pm, __shfl_xor(pm, 32));

    // exact online softmax: true running max, branchless rescale (P <= 1)
    const float mnew = fmaxf(m, pm);
    const float alpha = __expf(m - mnew);
    m = mnew;
    l *= alpha;
#pragma unroll
    for (int r = 0; r < 16; ++r) { o0[r] *= alpha; o1[r] *= alpha; }

    float tl = 0.f;
#pragma unroll
    for (int r = 0; r < 16; ++r) {
      st0[r] = __expf(st0[r] - mnew); tl += st0[r];
      st1[r] = __expf(st1[r] - mnew); tl += st1[r];
    }
    l += tl + __shfl_xor(tl, 32);

    // PV: A = V^T (row=d, k=key), B = P^T built in-register via shfl_xor
#pragma unroll
    for (int ks = 0; ks < 4; ++ks) {
      const f32x16& p = (ks < 2) ? st0 : st1;
      const int a = 8 * (ks & 1);
      unsigned w0 = pk2(p[a + 0], p[a + 1]);
      unsigned w1 = pk2(p[a + 2], p[a + 3]);
      unsigned w2 = pk2(p[a + 4], p[a + 5]);
      unsigned w3 = pk2(p[a + 6], p[a + 7]);
      unsigned x0 = (unsigned)__shfl_xor((int)w0, 32);
      unsigned x1 = (unsigned)__shfl_xor((int)w1, 32);
      unsigned x2 = (unsigned)__shfl_xor((int)w2, 32);
      unsigned x3 = (unsigned)__shfl_xor((int)w3, 32);
      int4v pi;
      pi[0] = (int)(hi ? x2 : w0);
      pi[1] = (int)(hi ? x3 : w1);
      pi[2] = (int)(hi ? w2 : x0);
      pi[3] = (int)(hi ? w3 : x1);
      short8 pb = __builtin_bit_cast(short8, pi);
      short8 v0 = ld8(vb + xo[ks]);
      short8 v1 = ld8(vb + 4096 + xo[ks]);
      o0 = mfma32(v0, pb, o0);
      o1 = mfma32(v1, pb, o1);
    }
    __syncthreads();
  }

  const float inv = 1.f / l;
  const int b = bh >> 4, h = bh & 15;
  float* Op = AO + ((size_t)(b * S_LEN + q0 + ql)) * DMODEL + h * DHEAD;
  // d = (r&3) + 8*(r>>2) + 4*hi -> regs 4g..4g+3 are 4 consecutive floats
  // at offset 8g + 4hi; 16B-aligned -> f32x4 stores.
#pragma unroll
  for (int gidx = 0; gidx < 4; ++gidx) {
    f32x4 s0, s1;
#pragma unroll
    for (int r = 0; r < 4; ++r) {
      s0[r] = o0[gidx * 4 + r] * inv;
      s1[r] = o1[gidx * 4 + r] * inv;
    }
    *reinterpret_cast<f32x4*>(Op + 8 * gidx + 4 * hi)      = s0;
    *reinterpret_cast<f32x4*>(Op + 32 + 8 * gidx + 4 * hi) = s1;
  }
}

extern "C" void kernel_launch(void* const* d_in, const int* in_sizes, int n_in,
                              void* d_out, int out_size, void* d_ws, size_t ws_size,
                              hipStream_t stream) {
  const float* query = (const float*)d_in[0];
  const float* key   = (const float*)d_in[1];
  const float* value = (const float*)d_in[2];
  const float* Wq = (const float*)d_in[3];  const float* bq = (const float*)d_in[4];
  const float* Wk = (const float*)d_in[5];  const float* bk = (const float*)d_in[6];
  const float* Wv = (const float*)d_in[7];  const float* bv = (const float*)d_in[8];
  const float* Wo = (const float*)d_in[9];  const float* bo = (const float*)d_in[10];

  const size_t MB = 1024u * 1024u;
  unsigned short* Qp = (unsigned short*)((char*)d_ws + 0 * MB);   // [32][2048][64] bf16, 8MB
  unsigned short* Kp = (unsigned short*)((char*)d_ws + 8 * MB);   // [32][2048][64] bf16, 8MB
  unsigned short* Vt = (unsigned short*)((char*)d_ws + 16 * MB);  // [32][64][2048] bf16, 8MB
  float*          AO = (float*)((char*)d_ws + 24 * MB);           // [4096][1024] fp32, 16MB

  GArgs g1;
  g1.A[0] = query; g1.A[1] = key; g1.A[2] = value;
  g1.W[0] = Wq;    g1.W[1] = Wk;  g1.W[2] = Wv;
  g1.bia[0] = bq;  g1.bia[1] = bk; g1.bia[2] = bv;
  g1.out[0] = Qp;  g1.out[1] = Kp; g1.out[2] = Vt;
  g1.epi[0] = 0;   g1.epi[1] = 1;  g1.epi[2] = 2;
  gemm_bt<<<dim3(NDIM / BN, MROWS / BM, 3), 256, 0, stream>>>(g1);

  attn_fwd<<<dim3(BHN * 16), 256, 0, stream>>>(Qp, Kp, Vt, AO);

  GArgs g2 = {};
  g2.A[0] = AO; g2.W[0] = Wo; g2.bia[0] = bo; g2.out[0] = d_out; g2.epi[0] = 3;
  gemm_bt<<<dim3(NDIM / BN, MROWS / BM, 1), 256, 0, stream>>>(g2);
}

// Round 6
// 164.478 us; speedup vs baseline: 2.1341x; 1.1591x over previous
//
#include <hip/hip_runtime.h>
#include <hip/hip_bf16.h>

typedef __attribute__((ext_vector_type(8))) short short8;
typedef __attribute__((ext_vector_type(4))) short short4v;
typedef __attribute__((ext_vector_type(4))) float f32x4;
typedef __attribute__((ext_vector_type(16))) float f32x16;
typedef __attribute__((ext_vector_type(4))) int int4v;
typedef __attribute__((ext_vector_type(2))) int int2v;

#define DEV static __device__ __forceinline__

constexpr int S_LEN   = 2048;
constexpr int DMODEL  = 1024;
constexpr int NHEAD   = 16;
constexpr int DHEAD   = 64;
constexpr int NBATCH  = 2;
constexpr int BHN     = NBATCH * NHEAD;   // 32
constexpr int MROWS   = NBATCH * S_LEN;   // 4096
constexpr int NDIM    = DMODEL;

DEV unsigned short f2b(float f) {
  __hip_bfloat16 h = __float2bfloat16(f);
  return __builtin_bit_cast(unsigned short, h);
}
DEV unsigned pk2(float a, float b) {
  return (unsigned)f2b(a) | ((unsigned)f2b(b) << 16);
}
DEV short8 ld8(const void* p) {
  return *reinterpret_cast<const short8*>(p);
}
DEV f32x4 mfma16(short8 a, short8 b, f32x4 c) {
  return __builtin_amdgcn_mfma_f32_16x16x32_bf16(a, b, c, 0, 0, 0);
}
DEV f32x16 mfma32(short8 a, short8 b, f32x16 c) {
  return __builtin_amdgcn_mfma_f32_32x32x16_bf16(a, b, c, 0, 0, 0);
}
DEV void gload16(const void* g, void* l) {
  __builtin_amdgcn_global_load_lds(
      (const __attribute__((address_space(1))) unsigned*)g,
      (__attribute__((address_space(3))) unsigned*)l, 16, 0, 0);
}

// ---------------------------------------------------------------------------
// fp32 -> bf16 conversion pass (memory-bound, ~96 MB traffic)
// ---------------------------------------------------------------------------
struct CvtArgs {
  const float* src[7];
  unsigned short* dst[7];
  int n4[7];   // element count / 4
};

__global__ __launch_bounds__(256) void cvt_bf16(CvtArgs c) {
  const int seg = blockIdx.y;
  const float* __restrict__ s = c.src[seg];
  unsigned short* __restrict__ d = c.dst[seg];
  const int n4 = c.n4[seg];
  for (int i = blockIdx.x * 256 + threadIdx.x; i < n4; i += gridDim.x * 256) {
    f32x4 v = reinterpret_cast<const f32x4*>(s)[i];
    short4v r;
    r[0] = (short)f2b(v[0]); r[1] = (short)f2b(v[1]);
    r[2] = (short)f2b(v[2]); r[3] = (short)f2b(v[3]);
    reinterpret_cast<short4v*>(d)[i] = r;
  }
}

// ---------------------------------------------------------------------------
// bf16 NT GEMM, m97 structure: 128x128 tile, BK=32, global_load_lds width-16
// into double-buffered linear LDS, ONE barrier per K-step, 16 MFMA/step/wave.
// C[row,col] = sum_k A[row,k]*W[col,k] + bia[col]
// ---------------------------------------------------------------------------
struct GB {
  const unsigned short* A[3];   // [M][1024] bf16 row-major
  const unsigned short* W[3];   // [1024][1024] bf16 row-major (NT)
  const float* bia[3];
  void* out[3];
  int epi[3];   // 0=Q(scaled) 1=K 2=V(transposed) 3=final(fp32)
};

__global__ __launch_bounds__(256, 2) void gemm_bf16(GB g) {
  const int z = blockIdx.z;
  const unsigned short* __restrict__ A = g.A[z];
  const unsigned short* __restrict__ W = g.W[z];
  const float* __restrict__ bia = g.bia[z];
  const int epi = g.epi[z];
  const int bm = blockIdx.y, bn = blockIdx.x;
  const int tid = threadIdx.x, lane = tid & 63, wid = tid >> 6;
  const int wr = wid >> 1, wc = wid & 1;          // 2x2 waves, 64x64 each
  const int fr = lane & 15, gq = lane >> 4;

  __shared__ unsigned short As[2][128][32];   // 8 KB x2
  __shared__ unsigned short Bs[2][128][32];   // 8 KB x2

  f32x4 acc[4][4] = {};

  // staging: per call-site a wave covers 16 rows (4 lanes x 16B per 64B row)
  const int srow = lane >> 2;
  const int scol = (lane & 3) * 16;
  const char* aS = (const char*)A + (size_t)(bm * 128 + wid * 16 + srow) * 2048 + scol;
  const char* bS = (const char*)W + (size_t)(bn * 128 + wid * 16 + srow) * 2048 + scol;

  auto stage = [&](int buf, int kt) {
    const int ko = kt * 64;   // byte offset within a 2048B row
    char* a0 = (char*)As[buf] + wid * 1024;
    char* b0 = (char*)Bs[buf] + wid * 1024;
    gload16(aS + ko, a0);
    gload16(aS + (size_t)64 * 2048 + ko, a0 + 4096);
    gload16(bS + ko, b0);
    gload16(bS + (size_t)64 * 2048 + ko, b0 + 4096);
  };

  stage(0, 0);
  __syncthreads();
  for (int kt = 0; kt < 32; ++kt) {
    const int buf = kt & 1;
    if (kt + 1 < 32) stage(buf ^ 1, kt + 1);
    short8 af[4], bf4[4];
#pragma unroll
    for (int i = 0; i < 4; ++i) af[i] = ld8(&As[buf][wr * 64 + i * 16 + fr][gq * 8]);
#pragma unroll
    for (int j = 0; j < 4; ++j) bf4[j] = ld8(&Bs[buf][wc * 64 + j * 16 + fr][gq * 8]);
#pragma unroll
    for (int i = 0; i < 4; ++i)
#pragma unroll
      for (int j = 0; j < 4; ++j)
        acc[i][j] = mfma16(af[i], bf4[j], acc[i][j]);
    __syncthreads();
  }

  // epilogue: C row = gq*4+r, col = fr (within each 16x16 fragment)
#pragma unroll
  for (int i = 0; i < 4; ++i) {
#pragma unroll
    for (int j = 0; j < 4; ++j) {
#pragma unroll
      for (int r = 0; r < 4; ++r) {
        const int row = bm * 128 + wr * 64 + i * 16 + gq * 4 + r;
        const int col = bn * 128 + wc * 64 + j * 16 + fr;
        float v = acc[i][j][r] + bia[col];
        if (epi == 3) {
          ((float*)g.out[z])[(size_t)row * NDIM + col] = v;
        } else {
          const int b = row >> 11, s = row & (S_LEN - 1);
          const int h = col >> 6,  dh = col & (DHEAD - 1);
          unsigned short* O = (unsigned short*)g.out[z];
          if (epi == 0)      O[((size_t)(b * NHEAD + h) * S_LEN + s) * DHEAD + dh] = f2b(v * 0.125f);
          else if (epi == 1) O[((size_t)(b * NHEAD + h) * S_LEN + s) * DHEAD + dh] = f2b(v);
          else               O[((size_t)(b * NHEAD + h) * DHEAD + dh) * S_LEN + s] = f2b(v);
        }
      }
    }
  }
}

// ---------------------------------------------------------------------------
// Flash attention, 4-wave 32x32 structure (512 blocks -> 2 blocks/CU).
// Identical to the round-5 passing kernel except the epilogue writes bf16
// (the final GEMM consumed AO via fp32->bf16 conversion anyway; numerics
// unchanged, AO traffic halved).
// ---------------------------------------------------------------------------
__global__ __launch_bounds__(256, 2) void attn_fwd(
    const unsigned short* __restrict__ Qp,
    const unsigned short* __restrict__ Kp,
    const unsigned short* __restrict__ Vt,
    unsigned short* __restrict__ AO) {
  // T1 bijective XCD swizzle: 512 blocks / 8 XCDs -> 4 heads per XCD (2MB L2)
  const int nb = (blockIdx.x & 7) * 64 + (blockIdx.x >> 3);
  const int qt = nb & 15, bh = nb >> 4;
  const int tid = threadIdx.x, lane = tid & 63, wid = tid >> 6;
  const int ql = lane & 31, hi = lane >> 5, l7 = lane & 7, l3 = lane >> 3;

  const unsigned short* Qh = Qp + (size_t)bh * S_LEN * DHEAD;
  const char* Kh = (const char*)(Kp + (size_t)bh * S_LEN * DHEAD);
  const char* Vh = (const char*)(Vt + (size_t)bh * DHEAD * S_LEN);

  __shared__ unsigned short Klds[2][4096];   // [64 keys][64 dh] swizzled, 8KB x2
  __shared__ unsigned short Vlds[2][4096];   // [64 dh][64 keys] swizzled, 8KB x2

  const int q0 = qt * 128 + wid * 32;
  short8 qf[4];
#pragma unroll
  for (int d16 = 0; d16 < 4; ++d16)
    qf[d16] = ld8(Qh + (size_t)(q0 + ql) * DHEAD + d16 * 16 + hi * 8);

  const int swc = (l7 ^ l3) << 4;
  const char* kS = Kh + (wid * 16 + l3) * 128 + swc;    // K row stride 128B
  const char* vS = Vh + (wid * 16 + l3) * 4096 + swc;   // Vt row stride 4096B
  char* kD0 = (char*)Klds[0] + wid * 2048;
  char* vD0 = (char*)Vlds[0] + wid * 2048;
  char* kD1 = (char*)Klds[1] + wid * 2048;
  char* vD1 = (char*)Vlds[1] + wid * 2048;

  int xo[4];
#pragma unroll
  for (int j = 0; j < 4; ++j) xo[j] = ((j * 2 + hi) ^ l7) << 4;

  float m = -1e30f, l = 0.f;
  f32x16 o0 = {}, o1 = {};    // O^T accum: col=q=ql, rows d (+0 / +32)

  gload16(kS, kD0); gload16(kS + 1024, kD0 + 1024);
  gload16(vS, vD0); gload16(vS + 32768, vD0 + 1024);
  __syncthreads();

  for (int kt = 0; kt < S_LEN / 64; ++kt) {
    const int buf = kt & 1;
    if (kt + 1 < S_LEN / 64) {
      const char* kn = kS + (kt + 1) * 8192;
      const char* vn = vS + (kt + 1) * 128;
      char* kD = buf ? kD0 : kD1;
      char* vD = buf ? vD0 : vD1;
      gload16(kn, kD); gload16(kn + 1024, kD + 1024);
      gload16(vn, vD); gload16(vn + 32768, vD + 1024);
    }
    const char* kb = (const char*)Klds[buf] + ql * 128;
    const char* vb = (const char*)Vlds[buf] + ql * 128;

    // QK^T swapped: A=K (row=key), B=Q (col=q) -> S^T[key][q]
    f32x16 st0 = {}, st1 = {};
#pragma unroll
    for (int d16 = 0; d16 < 4; ++d16) {
      short8 k0 = ld8(kb + xo[d16]);
      short8 k1 = ld8(kb + 4096 + xo[d16]);
      st0 = mfma32(k0, qf[d16], st0);
      st1 = mfma32(k1, qf[d16], st1);
    }

    float pm = fmaxf(st0[0], st1[0]);
#pragma unroll
    for (int r = 1; r < 16; ++r) pm = fmaxf(pm, fmaxf(st0[r], st1[r]));
    pm = fmaxf(pm, __shfl_xor(pm, 32));

    const float mnew = fmaxf(m, pm);
    const float alpha = __expf(m - mnew);
    m = mnew;
    l *= alpha;
#pragma unroll
    for (int r = 0; r < 16; ++r) { o0[r] *= alpha; o1[r] *= alpha; }

    float tl = 0.f;
#pragma unroll
    for (int r = 0; r < 16; ++r) {
      st0[r] = __expf(st0[r] - mnew); tl += st0[r];
      st1[r] = __expf(st1[r] - mnew); tl += st1[r];
    }
    l += tl + __shfl_xor(tl, 32);

    // PV: A = V^T (row=d, k=key), B = P^T built in-register via shfl_xor
#pragma unroll
    for (int ks = 0; ks < 4; ++ks) {
      const f32x16& p = (ks < 2) ? st0 : st1;
      const int a = 8 * (ks & 1);
      unsigned w0 = pk2(p[a + 0], p[a + 1]);
      unsigned w1 = pk2(p[a + 2], p[a + 3]);
      unsigned w2 = pk2(p[a + 4], p[a + 5]);
      unsigned w3 = pk2(p[a + 6], p[a + 7]);
      unsigned x0 = (unsigned)__shfl_xor((int)w0, 32);
      unsigned x1 = (unsigned)__shfl_xor((int)w1, 32);
      unsigned x2 = (unsigned)__shfl_xor((int)w2, 32);
      unsigned x3 = (unsigned)__shfl_xor((int)w3, 32);
      int4v pi;
      pi[0] = (int)(hi ? x2 : w0);
      pi[1] = (int)(hi ? x3 : w1);
      pi[2] = (int)(hi ? w2 : x0);
      pi[3] = (int)(hi ? w3 : x1);
      short8 pb = __builtin_bit_cast(short8, pi);
      short8 v0 = ld8(vb + xo[ks]);
      short8 v1 = ld8(vb + 4096 + xo[ks]);
      o0 = mfma32(v0, pb, o0);
      o1 = mfma32(v1, pb, o1);
    }
    __syncthreads();
  }

  const float inv = 1.f / l;
  const int b = bh >> 4, h = bh & 15;
  unsigned short* Op = AO + ((size_t)(b * S_LEN + q0 + ql)) * DMODEL + h * DHEAD;
  // d = (r&3) + 8*(r>>2) + 4*hi -> regs 4g..4g+3 = 4 consecutive bf16 (8B)
#pragma unroll
  for (int gidx = 0; gidx < 4; ++gidx) {
    int2v s0, s1;
    s0[0] = (int)pk2(o0[gidx * 4 + 0] * inv, o0[gidx * 4 + 1] * inv);
    s0[1] = (int)pk2(o0[gidx * 4 + 2] * inv, o0[gidx * 4 + 3] * inv);
    s1[0] = (int)pk2(o1[gidx * 4 + 0] * inv, o1[gidx * 4 + 1] * inv);
    s1[1] = (int)pk2(o1[gidx * 4 + 2] * inv, o1[gidx * 4 + 3] * inv);
    *reinterpret_cast<int2v*>(Op + 8 * gidx + 4 * hi)      = s0;
    *reinterpret_cast<int2v*>(Op + 32 + 8 * gidx + 4 * hi) = s1;
  }
}

extern "C" void kernel_launch(void* const* d_in, const int* in_sizes, int n_in,
                              void* d_out, int out_size, void* d_ws, size_t ws_size,
                              hipStream_t stream) {
  const float* query = (const float*)d_in[0];
  const float* key   = (const float*)d_in[1];
  const float* value = (const float*)d_in[2];
  const float* Wq = (const float*)d_in[3];  const float* bq = (const float*)d_in[4];
  const float* Wk = (const float*)d_in[5];  const float* bk = (const float*)d_in[6];
  const float* Wv = (const float*)d_in[7];  const float* bv = (const float*)d_in[8];
  const float* Wo = (const float*)d_in[9];  const float* bo = (const float*)d_in[10];

  const size_t MB = 1024u * 1024u;
  // ws layout (56 MB):
  //   [0,24)  Xb: query/key/value bf16, 8MB each.  AOb overlays [0,8) —
  //           Xb[query] is dead once the QKV GEMM dispatch completes.
  //   [24,30) Wb: Wq/Wk/Wv bf16, 2MB each
  //   [30,32) Wob
  //   [32,40) Qp   [40,48) Kp   [48,56) Vt
  unsigned short* Xb  = (unsigned short*)((char*)d_ws + 0 * MB);
  unsigned short* Wb  = (unsigned short*)((char*)d_ws + 24 * MB);
  unsigned short* Wob = (unsigned short*)((char*)d_ws + 30 * MB);
  unsigned short* Qp  = (unsigned short*)((char*)d_ws + 32 * MB);
  unsigned short* Kp  = (unsigned short*)((char*)d_ws + 40 * MB);
  unsigned short* Vt  = (unsigned short*)((char*)d_ws + 48 * MB);
  unsigned short* AOb = (unsigned short*)((char*)d_ws + 0 * MB);   // overlays Xb[query]

  const int NACT = MROWS * DMODEL;      // 4M elems
  const int NWT  = DMODEL * DMODEL;     // 1M elems

  CvtArgs ca;
  ca.src[0] = query; ca.dst[0] = Xb;            ca.n4[0] = NACT / 4;
  ca.src[1] = key;   ca.dst[1] = Xb + NACT;     ca.n4[1] = NACT / 4;
  ca.src[2] = value; ca.dst[2] = Xb + 2 * NACT; ca.n4[2] = NACT / 4;
  ca.src[3] = Wq;    ca.dst[3] = Wb;            ca.n4[3] = NWT / 4;
  ca.src[4] = Wk;    ca.dst[4] = Wb + NWT;      ca.n4[4] = NWT / 4;
  ca.src[5] = Wv;    ca.dst[5] = Wb + 2 * NWT;  ca.n4[5] = NWT / 4;
  ca.src[6] = Wo;    ca.dst[6] = Wob;           ca.n4[6] = NWT / 4;
  cvt_bf16<<<dim3(512, 7), 256, 0, stream>>>(ca);

  GB g1;
  g1.A[0] = Xb;            g1.A[1] = Xb + NACT; g1.A[2] = Xb + 2 * NACT;
  g1.W[0] = Wb;            g1.W[1] = Wb + NWT;  g1.W[2] = Wb + 2 * NWT;
  g1.bia[0] = bq;  g1.bia[1] = bk; g1.bia[2] = bv;
  g1.out[0] = Qp;  g1.out[1] = Kp; g1.out[2] = Vt;
  g1.epi[0] = 0;   g1.epi[1] = 1;  g1.epi[2] = 2;
  gemm_bf16<<<dim3(NDIM / 128, MROWS / 128, 3), 256, 0, stream>>>(g1);

  attn_fwd<<<dim3(BHN * 16), 256, 0, stream>>>(Qp, Kp, Vt, AOb);

  GB g2 = {};
  g2.A[0] = AOb; g2.W[0] = Wob; g2.bia[0] = bo; g2.out[0] = d_out; g2.epi[0] = 3;
  gemm_bf16<<<dim3(NDIM / 128, MROWS / 128, 1), 256, 0, stream>>>(g2);
}

// Round 7
// 156.316 us; speedup vs baseline: 2.2456x; 1.0522x over previous
//
#include <hip/hip_runtime.h>
#include <hip/hip_bf16.h>

typedef __attribute__((ext_vector_type(8))) short short8;
typedef __attribute__((ext_vector_type(4))) short short4v;
typedef __attribute__((ext_vector_type(4))) float f32x4;
typedef __attribute__((ext_vector_type(16))) float f32x16;
typedef __attribute__((ext_vector_type(4))) int int4v;
typedef __attribute__((ext_vector_type(2))) int int2v;

#define DEV static __device__ __forceinline__

constexpr int S_LEN   = 2048;
constexpr int DMODEL  = 1024;
constexpr int NHEAD   = 16;
constexpr int DHEAD   = 64;
constexpr int NBATCH  = 2;
constexpr int BHN     = NBATCH * NHEAD;   // 32
constexpr int MROWS   = NBATCH * S_LEN;   // 4096
constexpr int NDIM    = DMODEL;

DEV unsigned short f2b(float f) {
  __hip_bfloat16 h = __float2bfloat16(f);
  return __builtin_bit_cast(unsigned short, h);
}
DEV unsigned pk2(float a, float b) {
  return (unsigned)f2b(a) | ((unsigned)f2b(b) << 16);
}
DEV short8 ld8(const void* p) {
  return *reinterpret_cast<const short8*>(p);
}
DEV f32x4 mfma16(short8 a, short8 b, f32x4 c) {
  return __builtin_amdgcn_mfma_f32_16x16x32_bf16(a, b, c, 0, 0, 0);
}
DEV f32x16 mfma32(short8 a, short8 b, f32x16 c) {
  return __builtin_amdgcn_mfma_f32_32x32x16_bf16(a, b, c, 0, 0, 0);
}
DEV void gload16(const void* g, void* l) {
  __builtin_amdgcn_global_load_lds(
      (const __attribute__((address_space(1))) unsigned*)g,
      (__attribute__((address_space(3))) unsigned*)l, 16, 0, 0);
}

// ---------------------------------------------------------------------------
// fp32 -> bf16 conversion pass (memory-bound, ~96 MB traffic)
// ---------------------------------------------------------------------------
struct CvtArgs {
  const float* src[7];
  unsigned short* dst[7];
  int n4[7];   // element count / 4
};

__global__ __launch_bounds__(256) void cvt_bf16(CvtArgs c) {
  const int seg = blockIdx.y;
  const float* __restrict__ s = c.src[seg];
  unsigned short* __restrict__ d = c.dst[seg];
  const int n4 = c.n4[seg];
  for (int i = blockIdx.x * 256 + threadIdx.x; i < n4; i += gridDim.x * 256) {
    f32x4 v = reinterpret_cast<const f32x4*>(s)[i];
    short4v r;
    r[0] = (short)f2b(v[0]); r[1] = (short)f2b(v[1]);
    r[2] = (short)f2b(v[2]); r[3] = (short)f2b(v[3]);
    reinterpret_cast<short4v*>(d)[i] = r;
  }
}

// ---------------------------------------------------------------------------
// bf16 NT GEMM, m97 structure: 128x128 tile, BK=32, global_load_lds width-16
// into double-buffered linear LDS, ONE barrier per K-step, 16 MFMA/step/wave.
// C[row,col] = sum_k A[row,k]*W[col,k] + bia[col]
// ---------------------------------------------------------------------------
struct GB {
  const unsigned short* A[3];   // [M][1024] bf16 row-major
  const unsigned short* W[3];   // [1024][1024] bf16 row-major (NT)
  const float* bia[3];
  void* out[3];
  int epi[3];   // 0=Q(scaled) 1=K 2=V(transposed) 3=final(fp32)
};

__global__ __launch_bounds__(256, 2) void gemm_bf16(GB g) {
  const int z = blockIdx.z;
  const unsigned short* __restrict__ A = g.A[z];
  const unsigned short* __restrict__ W = g.W[z];
  const float* __restrict__ bia = g.bia[z];
  const int epi = g.epi[z];
  const int bm = blockIdx.y, bn = blockIdx.x;
  const int tid = threadIdx.x, lane = tid & 63, wid = tid >> 6;
  const int wr = wid >> 1, wc = wid & 1;          // 2x2 waves, 64x64 each
  const int fr = lane & 15, gq = lane >> 4;

  __shared__ unsigned short As[2][128][32];   // 8 KB x2
  __shared__ unsigned short Bs[2][128][32];   // 8 KB x2

  f32x4 acc[4][4] = {};

  const int srow = lane >> 2;
  const int scol = (lane & 3) * 16;
  const char* aS = (const char*)A + (size_t)(bm * 128 + wid * 16 + srow) * 2048 + scol;
  const char* bS = (const char*)W + (size_t)(bn * 128 + wid * 16 + srow) * 2048 + scol;

  auto stage = [&](int buf, int kt) {
    const int ko = kt * 64;   // byte offset within a 2048B row
    char* a0 = (char*)As[buf] + wid * 1024;
    char* b0 = (char*)Bs[buf] + wid * 1024;
    gload16(aS + ko, a0);
    gload16(aS + (size_t)64 * 2048 + ko, a0 + 4096);
    gload16(bS + ko, b0);
    gload16(bS + (size_t)64 * 2048 + ko, b0 + 4096);
  };

  stage(0, 0);
  __syncthreads();
  for (int kt = 0; kt < 32; ++kt) {
    const int buf = kt & 1;
    if (kt + 1 < 32) stage(buf ^ 1, kt + 1);
    short8 af[4], bf4[4];
#pragma unroll
    for (int i = 0; i < 4; ++i) af[i] = ld8(&As[buf][wr * 64 + i * 16 + fr][gq * 8]);
#pragma unroll
    for (int j = 0; j < 4; ++j) bf4[j] = ld8(&Bs[buf][wc * 64 + j * 16 + fr][gq * 8]);
#pragma unroll
    for (int i = 0; i < 4; ++i)
#pragma unroll
      for (int j = 0; j < 4; ++j)
        acc[i][j] = mfma16(af[i], bf4[j], acc[i][j]);
    __syncthreads();
  }

  // epilogue: C row = gq*4+r, col = fr (within each 16x16 fragment)
#pragma unroll
  for (int i = 0; i < 4; ++i) {
#pragma unroll
    for (int j = 0; j < 4; ++j) {
#pragma unroll
      for (int r = 0; r < 4; ++r) {
        const int row = bm * 128 + wr * 64 + i * 16 + gq * 4 + r;
        const int col = bn * 128 + wc * 64 + j * 16 + fr;
        float v = acc[i][j][r] + bia[col];
        if (epi == 3) {
          ((float*)g.out[z])[(size_t)row * NDIM + col] = v;
        } else {
          const int b = row >> 11, s = row & (S_LEN - 1);
          const int h = col >> 6,  dh = col & (DHEAD - 1);
          unsigned short* O = (unsigned short*)g.out[z];
          if (epi == 0)      O[((size_t)(b * NHEAD + h) * S_LEN + s) * DHEAD + dh] = f2b(v * 0.125f);
          else if (epi == 1) O[((size_t)(b * NHEAD + h) * S_LEN + s) * DHEAD + dh] = f2b(v);
          else               O[((size_t)(b * NHEAD + h) * DHEAD + dh) * S_LEN + s] = f2b(v);
        }
      }
    }
  }
}

// ---------------------------------------------------------------------------
// Flash attention, split-KV x2 in-block.
// 8 waves: waves 0-3 (hw=0) process keys [0,1024), waves 4-7 (hw=1) keys
// [1024,2048), for the same 128 q-rows (32 q per wave, 32x32 MFMA).
// Each half has its own double-buffered swizzled K/V LDS (64 KiB total ->
// 2 blocks/CU x 8 waves = 16 waves/CU). Exact in-block fp32 merge at the end.
// T13 defer-max (skip O-rescale while pm <= m+8) + tree reductions.
// ---------------------------------------------------------------------------
__global__ __launch_bounds__(512, 2) void attn_fwd(
    const unsigned short* __restrict__ Qp,
    const unsigned short* __restrict__ Kp,
    const unsigned short* __restrict__ Vt,
    unsigned short* __restrict__ AO) {
  // bijective XCD swizzle: 512 blocks / 8 XCDs -> 4 heads per XCD (2MB L2)
  const int nb = (blockIdx.x & 7) * 64 + (blockIdx.x >> 3);
  const int qt = nb & 15, bh = nb >> 4;
  const int tid = threadIdx.x, lane = tid & 63, wid = tid >> 6;
  const int qw = wid & 3, hw = wid >> 2;
  const int ql = lane & 31, hi = lane >> 5, l7 = lane & 7, l3 = lane >> 3;

  const unsigned short* Qh = Qp + (size_t)bh * S_LEN * DHEAD;
  const char* Kh = (const char*)(Kp + (size_t)bh * S_LEN * DHEAD);
  const char* Vh = (const char*)(Vt + (size_t)bh * DHEAD * S_LEN);

  __shared__ unsigned short Klds[2][2][4096];   // [hw][buf][64 rows x 64] 32KB
  __shared__ unsigned short Vlds[2][2][4096];   // [hw][buf]               32KB

  const int q0 = qt * 128 + qw * 32;
  short8 qf[4];
#pragma unroll
  for (int d16 = 0; d16 < 4; ++d16)
    qf[d16] = ld8(Qh + (size_t)(q0 + ql) * DHEAD + d16 * 16 + hi * 8);

  // staging: within a half, wave qw stages rows qw*16+[0,16); source column
  // chunk pre-swizzled by involution c ^= (row&7) so linear LDS dest works.
  const int swc = (l7 ^ l3) << 4;
  const char* kS = Kh + (size_t)hw * 16 * 8192 + (qw * 16 + l3) * 128 + swc;
  const char* vS = Vh + (size_t)hw * 16 * 128 + (qw * 16 + l3) * 4096 + swc;
  char* kD0 = (char*)Klds[hw][0] + qw * 2048;
  char* vD0 = (char*)Vlds[hw][0] + qw * 2048;
  char* kD1 = (char*)Klds[hw][1] + qw * 2048;
  char* vD1 = (char*)Vlds[hw][1] + qw * 2048;

  int xo[4];
#pragma unroll
  for (int j = 0; j < 4; ++j) xo[j] = ((j * 2 + hi) ^ l7) << 4;

  float m = -1e30f, l = 0.f;
  f32x16 o0 = {}, o1 = {};    // O^T accum: col=q=ql, rows d (+0 / +32)

  gload16(kS, kD0); gload16(kS + 1024, kD0 + 1024);
  gload16(vS, vD0); gload16(vS + 32768, vD0 + 1024);
  __syncthreads();

  constexpr int NT = S_LEN / 64 / 2;   // 16 tiles per half
  for (int kt = 0; kt < NT; ++kt) {
    const int buf = kt & 1;
    if (kt + 1 < NT) {
      const char* kn = kS + (kt + 1) * 8192;
      const char* vn = vS + (kt + 1) * 128;
      char* kD = buf ? kD0 : kD1;
      char* vD = buf ? vD0 : vD1;
      gload16(kn, kD); gload16(kn + 1024, kD + 1024);
      gload16(vn, vD); gload16(vn + 32768, vD + 1024);
    }
    const char* kb = (const char*)Klds[hw][buf] + ql * 128;
    const char* vb = (const char*)Vlds[hw][buf] + ql * 128;

    // QK^T swapped: A=K (row=key), B=Q (col=q) -> S^T[key][q]
    f32x16 st0 = {}, st1 = {};
#pragma unroll
    for (int d16 = 0; d16 < 4; ++d16) {
      short8 k0 = ld8(kb + xo[d16]);
      short8 k1 = ld8(kb + 4096 + xo[d16]);
      st0 = mfma32(k0, qf[d16], st0);
      st1 = mfma32(k1, qf[d16], st1);
    }

    // tile max: pairwise tree (depth ~5) + cross-half exchange
    float t8[8];
#pragma unroll
    for (int r = 0; r < 8; ++r)
      t8[r] = fmaxf(fmaxf(st0[r], st0[r + 8]), fmaxf(st1[r], st1[r + 8]));
#pragma unroll
    for (int s = 4; s; s >>= 1)
#pragma unroll
      for (int r = 0; r < s; ++r) t8[r] = fmaxf(t8[r], t8[r + s]);
    float pm = fmaxf(t8[0], __shfl_xor(t8[0], 32));

    // T13 defer-max: rescale only when some lane's max grew past m+8
    if (!__all(pm <= m + 8.f)) {
      const float mnew = fmaxf(m, pm);
      const float alpha = __expf(m - mnew);
      m = mnew;
      l *= alpha;
#pragma unroll
      for (int r = 0; r < 16; ++r) { o0[r] *= alpha; o1[r] *= alpha; }
    }

#pragma unroll
    for (int r = 0; r < 16; ++r) {
      st0[r] = __expf(st0[r] - m);
      st1[r] = __expf(st1[r] - m);
    }
    float s8[8];
#pragma unroll
    for (int r = 0; r < 8; ++r)
      s8[r] = (st0[r] + st0[r + 8]) + (st1[r] + st1[r + 8]);
#pragma unroll
    for (int s = 4; s; s >>= 1)
#pragma unroll
      for (int r = 0; r < s; ++r) s8[r] += s8[r + s];
    l += s8[0] + __shfl_xor(s8[0], 32);

    // PV: A = V^T (row=d, k=key), B = P^T built in-register via shfl_xor
#pragma unroll
    for (int ks = 0; ks < 4; ++ks) {
      const f32x16& p = (ks < 2) ? st0 : st1;
      const int a = 8 * (ks & 1);
      unsigned w0 = pk2(p[a + 0], p[a + 1]);
      unsigned w1 = pk2(p[a + 2], p[a + 3]);
      unsigned w2 = pk2(p[a + 4], p[a + 5]);
      unsigned w3 = pk2(p[a + 6], p[a + 7]);
      unsigned x0 = (unsigned)__shfl_xor((int)w0, 32);
      unsigned x1 = (unsigned)__shfl_xor((int)w1, 32);
      unsigned x2 = (unsigned)__shfl_xor((int)w2, 32);
      unsigned x3 = (unsigned)__shfl_xor((int)w3, 32);
      int4v pi;
      pi[0] = (int)(hi ? x2 : w0);
      pi[1] = (int)(hi ? x3 : w1);
      pi[2] = (int)(hi ? w2 : x0);
      pi[3] = (int)(hi ? w3 : x1);
      short8 pb = __builtin_bit_cast(short8, pi);
      short8 v0 = ld8(vb + xo[ks]);
      short8 v1 = ld8(vb + 4096 + xo[ks]);
      o0 = mfma32(v0, pb, o0);
      o1 = mfma32(v1, pb, o1);
    }
    __syncthreads();
  }

  // ---- in-block merge of the two KV halves (exact fp32) ----
  // upper half (hw=1) publishes m,l,O via LDS; lower half combines + writes.
  float* Kf = (float*)&Klds[0][0][0];   // 32KB: [qw][reg 0..31][lane]
  float* Vf = (float*)&Vlds[0][0][0];   // m,l:  [qw][{m,l}][lane]
  if (hw == 1) {
#pragma unroll
    for (int r = 0; r < 16; ++r) {
      Kf[qw * 2048 + r * 64 + lane]        = o0[r];
      Kf[qw * 2048 + (16 + r) * 64 + lane] = o1[r];
    }
    Vf[qw * 128 + lane]      = m;
    Vf[qw * 128 + 64 + lane] = l;
  }
  __syncthreads();
  if (hw == 0) {
    const float mb = Vf[qw * 128 + lane];
    const float lb = Vf[qw * 128 + 64 + lane];
    const float M  = fmaxf(m, mb);
    const float wa = __expf(m - M);
    const float wb = __expf(mb - M);
    const float inv = 1.f / (wa * l + wb * lb);
    const int b = bh >> 4, h = bh & 15;
    unsigned short* Op = AO + ((size_t)(b * S_LEN + q0 + ql)) * DMODEL + h * DHEAD;
#pragma unroll
    for (int gidx = 0; gidx < 4; ++gidx) {
      float f0[4], f1[4];
#pragma unroll
      for (int r = 0; r < 4; ++r) {
        const int rr = gidx * 4 + r;
        f0[r] = (wa * o0[rr] + wb * Kf[qw * 2048 + rr * 64 + lane]) * inv;
        f1[r] = (wa * o1[rr] + wb * Kf[qw * 2048 + (16 + rr) * 64 + lane]) * inv;
      }
      int2v s0, s1;
      s0[0] = (int)pk2(f0[0], f0[1]); s0[1] = (int)pk2(f0[2], f0[3]);
      s1[0] = (int)pk2(f1[0], f1[1]); s1[1] = (int)pk2(f1[2], f1[3]);
      *reinterpret_cast<int2v*>(Op + 8 * gidx + 4 * hi)      = s0;
      *reinterpret_cast<int2v*>(Op + 32 + 8 * gidx + 4 * hi) = s1;
    }
  }
}

extern "C" void kernel_launch(void* const* d_in, const int* in_sizes, int n_in,
                              void* d_out, int out_size, void* d_ws, size_t ws_size,
                              hipStream_t stream) {
  const float* query = (const float*)d_in[0];
  const float* key   = (const float*)d_in[1];
  const float* value = (const float*)d_in[2];
  const float* Wq = (const float*)d_in[3];  const float* bq = (const float*)d_in[4];
  const float* Wk = (const float*)d_in[5];  const float* bk = (const float*)d_in[6];
  const float* Wv = (const float*)d_in[7];  const float* bv = (const float*)d_in[8];
  const float* Wo = (const float*)d_in[9];  const float* bo = (const float*)d_in[10];

  const size_t MB = 1024u * 1024u;
  // ws layout (56 MB): [0,24) Xb (AOb overlays [0,8) after QKV GEMM);
  // [24,30) Wb; [30,32) Wob; [32,40) Qp; [40,48) Kp; [48,56) Vt
  unsigned short* Xb  = (unsigned short*)((char*)d_ws + 0 * MB);
  unsigned short* Wb  = (unsigned short*)((char*)d_ws + 24 * MB);
  unsigned short* Wob = (unsigned short*)((char*)d_ws + 30 * MB);
  unsigned short* Qp  = (unsigned short*)((char*)d_ws + 32 * MB);
  unsigned short* Kp  = (unsigned short*)((char*)d_ws + 40 * MB);
  unsigned short* Vt  = (unsigned short*)((char*)d_ws + 48 * MB);
  unsigned short* AOb = (unsigned short*)((char*)d_ws + 0 * MB);   // overlays Xb[query]

  const int NACT = MROWS * DMODEL;      // 4M elems
  const int NWT  = DMODEL * DMODEL;     // 1M elems

  CvtArgs ca;
  ca.src[0] = query; ca.dst[0] = Xb;            ca.n4[0] = NACT / 4;
  ca.src[1] = key;   ca.dst[1] = Xb + NACT;     ca.n4[1] = NACT / 4;
  ca.src[2] = value; ca.dst[2] = Xb + 2 * NACT; ca.n4[2] = NACT / 4;
  ca.src[3] = Wq;    ca.dst[3] = Wb;            ca.n4[3] = NWT / 4;
  ca.src[4] = Wk;    ca.dst[4] = Wb + NWT;      ca.n4[4] = NWT / 4;
  ca.src[5] = Wv;    ca.dst[5] = Wb + 2 * NWT;  ca.n4[5] = NWT / 4;
  ca.src[6] = Wo;    ca.dst[6] = Wob;           ca.n4[6] = NWT / 4;
  cvt_bf16<<<dim3(512, 7), 256, 0, stream>>>(ca);

  GB g1;
  g1.A[0] = Xb;            g1.A[1] = Xb + NACT; g1.A[2] = Xb + 2 * NACT;
  g1.W[0] = Wb;            g1.W[1] = Wb + NWT;  g1.W[2] = Wb + 2 * NWT;
  g1.bia[0] = bq;  g1.bia[1] = bk; g1.bia[2] = bv;
  g1.out[0] = Qp;  g1.out[1] = Kp; g1.out[2] = Vt;
  g1.epi[0] = 0;   g1.epi[1] = 1;  g1.epi[2] = 2;
  gemm_bf16<<<dim3(NDIM / 128, MROWS / 128, 3), 256, 0, stream>>>(g1);

  attn_fwd<<<dim3(BHN * 16), 512, 0, stream>>>(Qp, Kp, Vt, AOb);

  GB g2 = {};
  g2.A[0] = AOb; g2.W[0] = Wob; g2.bia[0] = bo; g2.out[0] = d_out; g2.epi[0] = 3;
  gemm_bf16<<<dim3(NDIM / 128, MROWS / 128, 1), 256, 0, stream>>>(g2);
}

// Round 8
// 154.318 us; speedup vs baseline: 2.2747x; 1.0129x over previous
//
#include <hip/hip_runtime.h>
#include <hip/hip_bf16.h>

typedef __attribute__((ext_vector_type(8))) short short8;
typedef __attribute__((ext_vector_type(4))) short short4v;
typedef __attribute__((ext_vector_type(4))) float f32x4;
typedef __attribute__((ext_vector_type(16))) float f32x16;
typedef __attribute__((ext_vector_type(4))) int int4v;
typedef __attribute__((ext_vector_type(2))) int int2v;

#define DEV static __device__ __forceinline__

constexpr int S_LEN   = 2048;
constexpr int DMODEL  = 1024;
constexpr int NHEAD   = 16;
constexpr int DHEAD   = 64;
constexpr int NBATCH  = 2;
constexpr int BHN     = NBATCH * NHEAD;   // 32
constexpr int MROWS   = NBATCH * S_LEN;   // 4096
constexpr int NDIM    = DMODEL;

DEV unsigned short f2b(float f) {
  __hip_bfloat16 h = __float2bfloat16(f);
  return __builtin_bit_cast(unsigned short, h);
}
DEV unsigned pk2(float a, float b) {
  return (unsigned)f2b(a) | ((unsigned)f2b(b) << 16);
}
DEV short8 ld8(const void* p) {
  return *reinterpret_cast<const short8*>(p);
}
DEV f32x4 mfma16(short8 a, short8 b, f32x4 c) {
  return __builtin_amdgcn_mfma_f32_16x16x32_bf16(a, b, c, 0, 0, 0);
}
DEV f32x16 mfma32(short8 a, short8 b, f32x16 c) {
  return __builtin_amdgcn_mfma_f32_32x32x16_bf16(a, b, c, 0, 0, 0);
}
DEV void gload16(const void* g, void* l) {
  __builtin_amdgcn_global_load_lds(
      (const __attribute__((address_space(1))) unsigned*)g,
      (__attribute__((address_space(3))) unsigned*)l, 16, 0, 0);
}

// ---------------------------------------------------------------------------
// fp32 -> bf16 conversion pass (memory-bound, ~96 MB traffic)
// ---------------------------------------------------------------------------
struct CvtArgs {
  const float* src[7];
  unsigned short* dst[7];
  int n4[7];   // element count / 4
};

__global__ __launch_bounds__(256) void cvt_bf16(CvtArgs c) {
  const int seg = blockIdx.y;
  const float* __restrict__ s = c.src[seg];
  unsigned short* __restrict__ d = c.dst[seg];
  const int n4 = c.n4[seg];
  for (int i = blockIdx.x * 256 + threadIdx.x; i < n4; i += gridDim.x * 256) {
    f32x4 v = reinterpret_cast<const f32x4*>(s)[i];
    short4v r;
    r[0] = (short)f2b(v[0]); r[1] = (short)f2b(v[1]);
    r[2] = (short)f2b(v[2]); r[3] = (short)f2b(v[3]);
    reinterpret_cast<short4v*>(d)[i] = r;
  }
}

// ---------------------------------------------------------------------------
// bf16 NT GEMM, 128x64 tile (1536 blocks -> 6 blocks/CU for the QKV shape),
// BK=32, global_load_lds width-16 into double-buffered LDS, one barrier per
// K-step, 8 MFMA/step/wave. 16B-chunk XOR swizzle (chunk ^= row&3) applied
// on the pre-swizzled global source AND on the ds_read offset (rule 21).
// C[row,col] = sum_k A[row,k]*W[col,k] + bia[col]
// ---------------------------------------------------------------------------
struct GB {
  const unsigned short* A[3];   // [M][1024] bf16 row-major
  const unsigned short* W[3];   // [1024][1024] bf16 row-major (NT)
  const float* bia[3];
  void* out[3];
  int epi[3];   // 0=Q(scaled) 1=K 2=V(transposed) 3=final(fp32)
};

__global__ __launch_bounds__(256, 4) void gemm_bf16(GB g) {
  const int z = blockIdx.z;
  const unsigned short* __restrict__ A = g.A[z];
  const unsigned short* __restrict__ W = g.W[z];
  const float* __restrict__ bia = g.bia[z];
  const int epi = g.epi[z];
  const int bm = blockIdx.y, bn = blockIdx.x;
  const int tid = threadIdx.x, lane = tid & 63, wid = tid >> 6;
  const int wr = wid >> 1, wc = wid & 1;          // 2x2 waves: 64x32 each
  const int fr = lane & 15, gq = lane >> 4;

  __shared__ unsigned short As[2][128][32];   // 8 KB x2
  __shared__ unsigned short Bs[2][64][32];    // 4 KB x2

  f32x4 acc[4][2] = {};

  // staging: lane covers row l>>2, chunk l&3 of a 16-row group; global
  // source chunk pre-swizzled by involution c ^= (row&3).
  const int srow = lane >> 2;
  const int scol = ((lane & 3) ^ (srow & 3)) * 16;
  const char* aS = (const char*)A + (size_t)(bm * 128 + wid * 32 + srow) * 2048 + scol;
  const char* bS = (const char*)W + (size_t)(bn * 64 + wid * 16 + srow) * 2048 + scol;

  auto stage = [&](int buf, int kt) {
    const int ko = kt * 64;   // byte offset within a 2048B row
    char* a0 = (char*)As[buf] + wid * 2048;
    char* b0 = (char*)Bs[buf] + wid * 1024;
    gload16(aS + ko, a0);
    gload16(aS + (size_t)16 * 2048 + ko, a0 + 1024);
    gload16(bS + ko, b0);
  };

  // swizzled read chunk: (gq ^ (row&3)), row&3 == fr&3 for all frag rows
  const int rdo = ((gq ^ (fr & 3)) * 8);

  stage(0, 0);
  __syncthreads();
  for (int kt = 0; kt < 32; ++kt) {
    const int buf = kt & 1;
    if (kt + 1 < 32) stage(buf ^ 1, kt + 1);
    short8 af[4], bf4[2];
#pragma unroll
    for (int i = 0; i < 4; ++i) af[i] = ld8(&As[buf][wr * 64 + i * 16 + fr][rdo]);
#pragma unroll
    for (int j = 0; j < 2; ++j) bf4[j] = ld8(&Bs[buf][wc * 32 + j * 16 + fr][rdo]);
#pragma unroll
    for (int i = 0; i < 4; ++i)
#pragma unroll
      for (int j = 0; j < 2; ++j)
        acc[i][j] = mfma16(af[i], bf4[j], acc[i][j]);
    __syncthreads();
  }

  // epilogue: C row = gq*4+r, col = fr (within each 16x16 fragment)
#pragma unroll
  for (int i = 0; i < 4; ++i) {
#pragma unroll
    for (int j = 0; j < 2; ++j) {
#pragma unroll
      for (int r = 0; r < 4; ++r) {
        const int row = bm * 128 + wr * 64 + i * 16 + gq * 4 + r;
        const int col = bn * 64 + wc * 32 + j * 16 + fr;
        float v = acc[i][j][r] + bia[col];
        if (epi == 3) {
          ((float*)g.out[z])[(size_t)row * NDIM + col] = v;
        } else {
          const int b = row >> 11, s = row & (S_LEN - 1);
          const int h = col >> 6,  dh = col & (DHEAD - 1);
          unsigned short* O = (unsigned short*)g.out[z];
          if (epi == 0)      O[((size_t)(b * NHEAD + h) * S_LEN + s) * DHEAD + dh] = f2b(v * 0.125f);
          else if (epi == 1) O[((size_t)(b * NHEAD + h) * S_LEN + s) * DHEAD + dh] = f2b(v);
          else               O[((size_t)(b * NHEAD + h) * DHEAD + dh) * S_LEN + s] = f2b(v);
        }
      }
    }
  }
}

// ---------------------------------------------------------------------------
// Flash attention, split-KV x2 in-block (unchanged from round 7, passing).
// ---------------------------------------------------------------------------
__global__ __launch_bounds__(512, 2) void attn_fwd(
    const unsigned short* __restrict__ Qp,
    const unsigned short* __restrict__ Kp,
    const unsigned short* __restrict__ Vt,
    unsigned short* __restrict__ AO) {
  const int nb = (blockIdx.x & 7) * 64 + (blockIdx.x >> 3);
  const int qt = nb & 15, bh = nb >> 4;
  const int tid = threadIdx.x, lane = tid & 63, wid = tid >> 6;
  const int qw = wid & 3, hw = wid >> 2;
  const int ql = lane & 31, hi = lane >> 5, l7 = lane & 7, l3 = lane >> 3;

  const unsigned short* Qh = Qp + (size_t)bh * S_LEN * DHEAD;
  const char* Kh = (const char*)(Kp + (size_t)bh * S_LEN * DHEAD);
  const char* Vh = (const char*)(Vt + (size_t)bh * DHEAD * S_LEN);

  __shared__ unsigned short Klds[2][2][4096];   // [hw][buf] 32KB
  __shared__ unsigned short Vlds[2][2][4096];   // [hw][buf] 32KB

  const int q0 = qt * 128 + qw * 32;
  short8 qf[4];
#pragma unroll
  for (int d16 = 0; d16 < 4; ++d16)
    qf[d16] = ld8(Qh + (size_t)(q0 + ql) * DHEAD + d16 * 16 + hi * 8);

  const int swc = (l7 ^ l3) << 4;
  const char* kS = Kh + (size_t)hw * 16 * 8192 + (qw * 16 + l3) * 128 + swc;
  const char* vS = Vh + (size_t)hw * 16 * 128 + (qw * 16 + l3) * 4096 + swc;
  char* kD0 = (char*)Klds[hw][0] + qw * 2048;
  char* vD0 = (char*)Vlds[hw][0] + qw * 2048;
  char* kD1 = (char*)Klds[hw][1] + qw * 2048;
  char* vD1 = (char*)Vlds[hw][1] + qw * 2048;

  int xo[4];
#pragma unroll
  for (int j = 0; j < 4; ++j) xo[j] = ((j * 2 + hi) ^ l7) << 4;

  float m = -1e30f, l = 0.f;
  f32x16 o0 = {}, o1 = {};

  gload16(kS, kD0); gload16(kS + 1024, kD0 + 1024);
  gload16(vS, vD0); gload16(vS + 32768, vD0 + 1024);
  __syncthreads();

  constexpr int NT = S_LEN / 64 / 2;   // 16 tiles per half
  for (int kt = 0; kt < NT; ++kt) {
    const int buf = kt & 1;
    if (kt + 1 < NT) {
      const char* kn = kS + (kt + 1) * 8192;
      const char* vn = vS + (kt + 1) * 128;
      char* kD = buf ? kD0 : kD1;
      char* vD = buf ? vD0 : vD1;
      gload16(kn, kD); gload16(kn + 1024, kD + 1024);
      gload16(vn, vD); gload16(vn + 32768, vD + 1024);
    }
    const char* kb = (const char*)Klds[hw][buf] + ql * 128;
    const char* vb = (const char*)Vlds[hw][buf] + ql * 128;

    f32x16 st0 = {}, st1 = {};
#pragma unroll
    for (int d16 = 0; d16 < 4; ++d16) {
      short8 k0 = ld8(kb + xo[d16]);
      short8 k1 = ld8(kb + 4096 + xo[d16]);
      st0 = mfma32(k0, qf[d16], st0);
      st1 = mfma32(k1, qf[d16], st1);
    }

    float t8[8];
#pragma unroll
    for (int r = 0; r < 8; ++r)
      t8[r] = fmaxf(fmaxf(st0[r], st0[r + 8]), fmaxf(st1[r], st1[r + 8]));
#pragma unroll
    for (int s = 4; s; s >>= 1)
#pragma unroll
      for (int r = 0; r < s; ++r) t8[r] = fmaxf(t8[r], t8[r + s]);
    float pm = fmaxf(t8[0], __shfl_xor(t8[0], 32));

    if (!__all(pm <= m + 8.f)) {
      const float mnew = fmaxf(m, pm);
      const float alpha = __expf(m - mnew);
      m = mnew;
      l *= alpha;
#pragma unroll
      for (int r = 0; r < 16; ++r) { o0[r] *= alpha; o1[r] *= alpha; }
    }

#pragma unroll
    for (int r = 0; r < 16; ++r) {
      st0[r] = __expf(st0[r] - m);
      st1[r] = __expf(st1[r] - m);
    }
    float s8[8];
#pragma unroll
    for (int r = 0; r < 8; ++r)
      s8[r] = (st0[r] + st0[r + 8]) + (st1[r] + st1[r + 8]);
#pragma unroll
    for (int s = 4; s; s >>= 1)
#pragma unroll
      for (int r = 0; r < s; ++r) s8[r] += s8[r + s];
    l += s8[0] + __shfl_xor(s8[0], 32);

#pragma unroll
    for (int ks = 0; ks < 4; ++ks) {
      const f32x16& p = (ks < 2) ? st0 : st1;
      const int a = 8 * (ks & 1);
      unsigned w0 = pk2(p[a + 0], p[a + 1]);
      unsigned w1 = pk2(p[a + 2], p[a + 3]);
      unsigned w2 = pk2(p[a + 4], p[a + 5]);
      unsigned w3 = pk2(p[a + 6], p[a + 7]);
      unsigned x0 = (unsigned)__shfl_xor((int)w0, 32);
      unsigned x1 = (unsigned)__shfl_xor((int)w1, 32);
      unsigned x2 = (unsigned)__shfl_xor((int)w2, 32);
      unsigned x3 = (unsigned)__shfl_xor((int)w3, 32);
      int4v pi;
      pi[0] = (int)(hi ? x2 : w0);
      pi[1] = (int)(hi ? x3 : w1);
      pi[2] = (int)(hi ? w2 : x0);
      pi[3] = (int)(hi ? w3 : x1);
      short8 pb = __builtin_bit_cast(short8, pi);
      short8 v0 = ld8(vb + xo[ks]);
      short8 v1 = ld8(vb + 4096 + xo[ks]);
      o0 = mfma32(v0, pb, o0);
      o1 = mfma32(v1, pb, o1);
    }
    __syncthreads();
  }

  float* Kf = (float*)&Klds[0][0][0];
  float* Vf = (float*)&Vlds[0][0][0];
  if (hw == 1) {
#pragma unroll
    for (int r = 0; r < 16; ++r) {
      Kf[qw * 2048 + r * 64 + lane]        = o0[r];
      Kf[qw * 2048 + (16 + r) * 64 + lane] = o1[r];
    }
    Vf[qw * 128 + lane]      = m;
    Vf[qw * 128 + 64 + lane] = l;
  }
  __syncthreads();
  if (hw == 0) {
    const float mb = Vf[qw * 128 + lane];
    const float lb = Vf[qw * 128 + 64 + lane];
    const float M  = fmaxf(m, mb);
    const float wa = __expf(m - M);
    const float wb = __expf(mb - M);
    const float inv = 1.f / (wa * l + wb * lb);
    const int b = bh >> 4, h = bh & 15;
    unsigned short* Op = AO + ((size_t)(b * S_LEN + q0 + ql)) * DMODEL + h * DHEAD;
#pragma unroll
    for (int gidx = 0; gidx < 4; ++gidx) {
      float f0[4], f1[4];
#pragma unroll
      for (int r = 0; r < 4; ++r) {
        const int rr = gidx * 4 + r;
        f0[r] = (wa * o0[rr] + wb * Kf[qw * 2048 + rr * 64 + lane]) * inv;
        f1[r] = (wa * o1[rr] + wb * Kf[qw * 2048 + (16 + rr) * 64 + lane]) * inv;
      }
      int2v s0, s1;
      s0[0] = (int)pk2(f0[0], f0[1]); s0[1] = (int)pk2(f0[2], f0[3]);
      s1[0] = (int)pk2(f1[0], f1[1]); s1[1] = (int)pk2(f1[2], f1[3]);
      *reinterpret_cast<int2v*>(Op + 8 * gidx + 4 * hi)      = s0;
      *reinterpret_cast<int2v*>(Op + 32 + 8 * gidx + 4 * hi) = s1;
    }
  }
}

extern "C" void kernel_launch(void* const* d_in, const int* in_sizes, int n_in,
                              void* d_out, int out_size, void* d_ws, size_t ws_size,
                              hipStream_t stream) {
  const float* query = (const float*)d_in[0];
  const float* key   = (const float*)d_in[1];
  const float* value = (const float*)d_in[2];
  const float* Wq = (const float*)d_in[3];  const float* bq = (const float*)d_in[4];
  const float* Wk = (const float*)d_in[5];  const float* bk = (const float*)d_in[6];
  const float* Wv = (const float*)d_in[7];  const float* bv = (const float*)d_in[8];
  const float* Wo = (const float*)d_in[9];  const float* bo = (const float*)d_in[10];

  const size_t MB = 1024u * 1024u;
  // ws layout (56 MB): [0,24) Xb (AOb overlays [0,8) after QKV GEMM);
  // [24,30) Wb; [30,32) Wob; [32,40) Qp; [40,48) Kp; [48,56) Vt
  unsigned short* Xb  = (unsigned short*)((char*)d_ws + 0 * MB);
  unsigned short* Wb  = (unsigned short*)((char*)d_ws + 24 * MB);
  unsigned short* Wob = (unsigned short*)((char*)d_ws + 30 * MB);
  unsigned short* Qp  = (unsigned short*)((char*)d_ws + 32 * MB);
  unsigned short* Kp  = (unsigned short*)((char*)d_ws + 40 * MB);
  unsigned short* Vt  = (unsigned short*)((char*)d_ws + 48 * MB);
  unsigned short* AOb = (unsigned short*)((char*)d_ws + 0 * MB);   // overlays Xb[query]

  const int NACT = MROWS * DMODEL;      // 4M elems
  const int NWT  = DMODEL * DMODEL;     // 1M elems

  CvtArgs ca;
  ca.src[0] = query; ca.dst[0] = Xb;            ca.n4[0] = NACT / 4;
  ca.src[1] = key;   ca.dst[1] = Xb + NACT;     ca.n4[1] = NACT / 4;
  ca.src[2] = value; ca.dst[2] = Xb + 2 * NACT; ca.n4[2] = NACT / 4;
  ca.src[3] = Wq;    ca.dst[3] = Wb;            ca.n4[3] = NWT / 4;
  ca.src[4] = Wk;    ca.dst[4] = Wb + NWT;      ca.n4[4] = NWT / 4;
  ca.src[5] = Wv;    ca.dst[5] = Wb + 2 * NWT;  ca.n4[5] = NWT / 4;
  ca.src[6] = Wo;    ca.dst[6] = Wob;           ca.n4[6] = NWT / 4;
  cvt_bf16<<<dim3(512, 7), 256, 0, stream>>>(ca);

  GB g1;
  g1.A[0] = Xb;            g1.A[1] = Xb + NACT; g1.A[2] = Xb + 2 * NACT;
  g1.W[0] = Wb;            g1.W[1] = Wb + NWT;  g1.W[2] = Wb + 2 * NWT;
  g1.bia[0] = bq;  g1.bia[1] = bk; g1.bia[2] = bv;
  g1.out[0] = Qp;  g1.out[1] = Kp; g1.out[2] = Vt;
  g1.epi[0] = 0;   g1.epi[1] = 1;  g1.epi[2] = 2;
  gemm_bf16<<<dim3(NDIM / 64, MROWS / 128, 3), 256, 0, stream>>>(g1);

  attn_fwd<<<dim3(BHN * 16), 512, 0, stream>>>(Qp, Kp, Vt, AOb);

  GB g2 = {};
  g2.A[0] = AOb; g2.W[0] = Wob; g2.bia[0] = bo; g2.out[0] = d_out; g2.epi[0] = 3;
  gemm_bf16<<<dim3(NDIM / 64, MROWS / 128, 1), 256, 0, stream>>>(g2);
}